// Round 3
// baseline (7807.598 us; speedup 1.0000x reference)
//
#include <hip/hip_runtime.h>
#include <math.h>

// Problem: B=16, M=1024, N=1024 fp32; 20 ADMM iterations.
// RHO=1, LAMBD=0.1, ALPHA=0.5 -> threshold = 0.05, scale-const = 0.05.
#define NB 16
#define NM 1024
#define NN 1024
#define NROWS (NB * NM)      // 16384 softmax rows of length 1024
#define TPB 256              // 4 waves/block, one row per wave
#define NGRID (NROWS / 4)    // 4096 blocks -> 16 blocks/CU offered

#define MINV 1e-40f
#define THR  0.05f   // ALPHA*LAMBD/RHO
#define SCLC 0.05f   // (1-ALPHA)*LAMBD/RHO
#define EPSL 1e-10f

// Wave-level (64-lane) reductions — no LDS, no barriers.
__device__ __forceinline__ float wred_max(float v) {
#pragma unroll
  for (int o = 32; o > 0; o >>= 1) v = fmaxf(v, __shfl_xor(v, o, 64));
  return v;
}
__device__ __forceinline__ float wred_sum(float v) {
#pragma unroll
  for (int o = 32; o > 0; o >>= 1) v += __shfl_xor(v, o, 64);
  return v;
}
__device__ __forceinline__ float softthr(float x) {
  return copysignf(fmaxf(fabsf(x) - THR, 0.0f), x);
}

// Layout: row = blockIdx.x*4 + wave; lane L covers cols {c*256 + L*4 + j}.
// All global accesses are coalesced float4 (1 KiB per wave instruction).

// Iteration 1: X = R_0, Z = 0 -> tmp = log R0'. R_1 = softmax(log R0').
// Accumulates colsum slice 0 = sum softthr(R_1)^2.
__global__ __launch_bounds__(TPB) void k_start(const float* __restrict__ R0,
                                               float* __restrict__ R,
                                               float* __restrict__ cs0) {
  __shared__ float lds[4 * NN];  // 16 KB: per-wave colsum partials
  const int lane = threadIdx.x & 63;
  const int wv = threadIdx.x >> 6;
  const size_t row = (size_t)blockIdx.x * 4 + wv;
  const size_t base = row * NN + (size_t)lane * 4;

  float t[4][4];
  float mloc = -3.4e38f;
#pragma unroll
  for (int c = 0; c < 4; ++c) {
    const float4 r4 = *(const float4*)(R0 + base + c * 256);
    const float r0[4] = {r4.x, r4.y, r4.z, r4.w};
#pragma unroll
    for (int j = 0; j < 4; ++j) {
      t[c][j] = logf(r0[j] == 0.f ? MINV : r0[j]);
      mloc = fmaxf(mloc, t[c][j]);
    }
  }
  const float mx = wred_max(mloc);
  float sloc = 0.f;
#pragma unroll
  for (int c = 0; c < 4; ++c)
#pragma unroll
    for (int j = 0; j < 4; ++j) {
      t[c][j] = expf(t[c][j] - mx);
      sloc += t[c][j];
    }
  const float inv = 1.0f / wred_sum(sloc);
#pragma unroll
  for (int c = 0; c < 4; ++c) {
    float rn[4], a[4];
#pragma unroll
    for (int j = 0; j < 4; ++j) {
      rn[j] = t[c][j] * inv;
      const float s = softthr(rn[j]);  // Z = 0
      a[j] = s * s;
    }
    *(float4*)(R + base + c * 256) = make_float4(rn[0], rn[1], rn[2], rn[3]);
    *(float4*)(&lds[wv * NN + c * 256 + lane * 4]) =
        make_float4(a[0], a[1], a[2], a[3]);
  }
  __syncthreads();
  const int col = threadIdx.x * 4;
  float4 s0 = *(float4*)(&lds[0 * NN + col]);
  float4 s1 = *(float4*)(&lds[1 * NN + col]);
  float4 s2 = *(float4*)(&lds[2 * NN + col]);
  float4 s3 = *(float4*)(&lds[3 * NN + col]);
  atomicAdd(&cs0[col + 0], (s0.x + s1.x) + (s2.x + s3.x));
  atomicAdd(&cs0[col + 1], (s0.y + s1.y) + (s2.y + s3.y));
  atomicAdd(&cs0[col + 2], (s0.z + s1.z) + (s2.z + s3.z));
  atomicAdd(&cs0[col + 3], (s0.w + s1.w) + (s2.w + s3.w));
}

// Fused iteration: scale from csPrev (inline), X_t, Z_t, R_{t+1}, and colsum
// accumulation into csNext for the next iteration. X never materialized.
// last==1 (it=19): Z_19 and colsum are dead -> skip those stores entirely.
__global__ __launch_bounds__(TPB) void k_ab(const float* __restrict__ R0,
                                            float* __restrict__ R,
                                            float* __restrict__ Z,
                                            const float* __restrict__ csPrev,
                                            float* __restrict__ csNext,
                                            int z_zero, int last) {
  __shared__ float lds[4 * NN];  // 16 KB
  const int lane = threadIdx.x & 63;
  const int wv = threadIdx.x >> 6;
  const size_t row = (size_t)blockIdx.x * 4 + wv;
  const size_t base = row * NN + (size_t)lane * 4;

  float t[4][4], zn[4][4];
  float mloc = -3.4e38f;
#pragma unroll
  for (int c = 0; c < 4; ++c) {
    const int coff = c * 256 + lane * 4;
    const float4 cs4 = *(const float4*)(csPrev + coff);       // L2-hot, 4 KB
    const float4 rv4 = *(const float4*)(R + base + c * 256);
    const float4 r04 = *(const float4*)(R0 + base + c * 256);
    float zv[4] = {0.f, 0.f, 0.f, 0.f};
    if (!z_zero) {
      const float4 z4 = *(const float4*)(Z + base + c * 256);
      zv[0] = z4.x; zv[1] = z4.y; zv[2] = z4.z; zv[3] = z4.w;
    }
    const float cs[4] = {cs4.x, cs4.y, cs4.z, cs4.w};
    const float rv[4] = {rv4.x, rv4.y, rv4.z, rv4.w};
    const float r0[4] = {r04.x, r04.y, r04.z, r04.w};
#pragma unroll
    for (int j = 0; j < 4; ++j) {
      const float cn = sqrtf(cs[j]);                          // col norm
      const float sc = fmaxf(1.0f - SCLC / (cn + EPSL), 0.0f);
      const float x = rv[j] + zv[j];          // R + Z/RHO, RHO=1
      const float s = softthr(x);
      const float X = sc * s;                 // X_t (never stored)
      zn[c][j] = zv[j] + (rv[j] - X);         // Z_t
      const float l0 = logf(r0[j] == 0.f ? MINV : r0[j]);
      const float lX = logf(X == 0.f ? MINV : X);
      t[c][j] = 0.5f * (l0 + lX - zn[c][j]);  // (log R0' + log X' - Z)/2
      mloc = fmaxf(mloc, t[c][j]);
    }
  }
  const float mx = wred_max(mloc);
  float sloc = 0.f;
#pragma unroll
  for (int c = 0; c < 4; ++c)
#pragma unroll
    for (int j = 0; j < 4; ++j) {
      t[c][j] = expf(t[c][j] - mx);
      sloc += t[c][j];
    }
  const float inv = 1.0f / wred_sum(sloc);
#pragma unroll
  for (int c = 0; c < 4; ++c) {
    float rn[4];
#pragma unroll
    for (int j = 0; j < 4; ++j) rn[j] = t[c][j] * inv;  // R_{t+1}
    *(float4*)(R + base + c * 256) = make_float4(rn[0], rn[1], rn[2], rn[3]);
    if (!last) {
      *(float4*)(Z + base + c * 256) =
          make_float4(zn[c][0], zn[c][1], zn[c][2], zn[c][3]);
      float a[4];
#pragma unroll
      for (int j = 0; j < 4; ++j) {
        const float s = softthr(rn[j] + zn[c][j]);  // next iter's s_td
        a[j] = s * s;
      }
      *(float4*)(&lds[wv * NN + c * 256 + lane * 4]) =
          make_float4(a[0], a[1], a[2], a[3]);
    }
  }
  if (!last) {
    __syncthreads();
    const int col = threadIdx.x * 4;
    float4 s0 = *(float4*)(&lds[0 * NN + col]);
    float4 s1 = *(float4*)(&lds[1 * NN + col]);
    float4 s2 = *(float4*)(&lds[2 * NN + col]);
    float4 s3 = *(float4*)(&lds[3 * NN + col]);
    atomicAdd(&csNext[col + 0], (s0.x + s1.x) + (s2.x + s3.x));
    atomicAdd(&csNext[col + 1], (s0.y + s1.y) + (s2.y + s3.y));
    atomicAdd(&csNext[col + 2], (s0.z + s1.z) + (s2.z + s3.z));
    atomicAdd(&csNext[col + 3], (s0.w + s1.w) + (s2.w + s3.w));
  }
}

extern "C" void kernel_launch(void* const* d_in, const int* in_sizes, int n_in,
                              void* d_out, int out_size, void* d_ws, size_t ws_size,
                              hipStream_t stream) {
  (void)in_sizes; (void)n_in; (void)out_size; (void)ws_size;
  const float* R0 = (const float*)d_in[0];
  float* R = (float*)d_out;                 // final R_20 lands in d_out
  float* Z = (float*)d_ws;                  // 64 MB
  // 20 colsum slices (80 KB), ping-ponged: slice t accumulated in iter t,
  // read in iter t+1. Zeroed once -> no per-iteration resets or finalize.
  float* cs = (float*)((char*)d_ws + (size_t)NROWS * NN * sizeof(float));

  hipMemsetAsync(cs, 0, 20 * NN * sizeof(float), stream);
  k_start<<<NGRID, TPB, 0, stream>>>(R0, R, cs);
  for (int it = 1; it < 20; ++it) {
    k_ab<<<NGRID, TPB, 0, stream>>>(R0, R, Z,
                                    cs + (size_t)(it - 1) * NN,
                                    cs + (size_t)it * NN,
                                    (it == 1) ? 1 : 0, (it == 19) ? 1 : 0);
  }
}

// Round 4
// 1391.620 us; speedup vs baseline: 5.6104x; 5.6104x over previous
//
#include <hip/hip_runtime.h>
#include <math.h>

// Problem: B=16, M=1024, N=1024 fp32; 20 ADMM iterations.
// RHO=1, LAMBD=0.1, ALPHA=0.5 -> threshold = 0.05, scale-const = 0.05.
#define NB 16
#define NM 1024
#define NN 1024
#define NROWS (NB * NM)   // 16384 softmax rows of length 1024
#define TPB 256           // 4 waves/block
#define WPB 4
#define RPW 2             // rows per wave
#define RPB (WPB * RPW)   // 8 rows per block
#define NGRID (NROWS / RPB)  // 2048 blocks -> 8 blocks/CU offered
#define KSLOT 16          // colsum atomic spread: chain = 2048/16 = 128/address

#define MINV 1e-40f
#define THR  0.05f   // ALPHA*LAMBD/RHO
#define SCLC 0.05f   // (1-ALPHA)*LAMBD/RHO
#define EPSL 1e-10f

// Wave-level (64-lane) reductions — no LDS, no barriers.
__device__ __forceinline__ float wred_max(float v) {
#pragma unroll
  for (int o = 32; o > 0; o >>= 1) v = fmaxf(v, __shfl_xor(v, o, 64));
  return v;
}
__device__ __forceinline__ float wred_sum(float v) {
#pragma unroll
  for (int o = 32; o > 0; o >>= 1) v += __shfl_xor(v, o, 64);
  return v;
}
__device__ __forceinline__ float softthr(float x) {
  return copysignf(fmaxf(fabsf(x) - THR, 0.0f), x);
}

// Layout: row = blockIdx.x*8 + wave*2 + rr; lane L covers cols {c*256+L*4+j}.
// All global accesses are coalesced float4 (1 KiB per wave instruction).

// Iteration 1: X = R_0, Z = 0 -> tmp = log R0'. R_1 = softmax(log R0').
// Accumulates colsum slice 0 (spread over KSLOT sub-slots).
__global__ __launch_bounds__(TPB) void k_start(const float* __restrict__ R0,
                                               float* __restrict__ R,
                                               float* __restrict__ cs0) {
  __shared__ float s_part[WPB * NN];  // 16 KB: per-wave colsum partials
  const int lane = threadIdx.x & 63;
  const int wv = threadIdx.x >> 6;
#pragma unroll
  for (int rr = 0; rr < RPW; ++rr) {
    const size_t row = (size_t)blockIdx.x * RPB + wv * RPW + rr;
    const size_t base = row * NN + (size_t)lane * 4;
    float t[4][4];
    float mloc = -3.4e38f;
#pragma unroll
    for (int c = 0; c < 4; ++c) {
      const float4 r4 = *(const float4*)(R0 + base + c * 256);
      const float r0[4] = {r4.x, r4.y, r4.z, r4.w};
#pragma unroll
      for (int j = 0; j < 4; ++j) {
        t[c][j] = logf(r0[j] == 0.f ? MINV : r0[j]);
        mloc = fmaxf(mloc, t[c][j]);
      }
    }
    const float mx = wred_max(mloc);
    float sloc = 0.f;
#pragma unroll
    for (int c = 0; c < 4; ++c)
#pragma unroll
      for (int j = 0; j < 4; ++j) {
        t[c][j] = expf(t[c][j] - mx);
        sloc += t[c][j];
      }
    const float inv = 1.0f / wred_sum(sloc);
#pragma unroll
    for (int c = 0; c < 4; ++c) {
      float rn[4], a[4];
#pragma unroll
      for (int j = 0; j < 4; ++j) {
        rn[j] = t[c][j] * inv;
        const float s = softthr(rn[j]);  // Z = 0
        a[j] = s * s;
      }
      *(float4*)(R + base + c * 256) = make_float4(rn[0], rn[1], rn[2], rn[3]);
      float* p = &s_part[wv * NN + c * 256 + lane * 4];
      if (rr == 0) {
        *(float4*)p = make_float4(a[0], a[1], a[2], a[3]);
      } else {
        float4 o = *(float4*)p;
        *(float4*)p = make_float4(o.x + a[0], o.y + a[1], o.z + a[2], o.w + a[3]);
      }
    }
  }
  __syncthreads();
  const int col = threadIdx.x * 4;
  float4 s0 = *(float4*)(&s_part[0 * NN + col]);
  float4 s1 = *(float4*)(&s_part[1 * NN + col]);
  float4 s2 = *(float4*)(&s_part[2 * NN + col]);
  float4 s3 = *(float4*)(&s_part[3 * NN + col]);
  float* dst = cs0 + (size_t)(blockIdx.x & (KSLOT - 1)) * NN + col;
  atomicAdd(dst + 0, (s0.x + s1.x) + (s2.x + s3.x));
  atomicAdd(dst + 1, (s0.y + s1.y) + (s2.y + s3.y));
  atomicAdd(dst + 2, (s0.z + s1.z) + (s2.z + s3.z));
  atomicAdd(dst + 3, (s0.w + s1.w) + (s2.w + s3.w));
}

// Fused iteration t: scale from csPrev (K-slot sum -> LDS), X_t, Z_t,
// R_{t+1}, colsum partials -> csNext (K-slot spread atomics).
// X never materialized. last==1: Z_19 / colsum are dead -> skip stores.
__global__ __launch_bounds__(TPB) void k_ab(const float* __restrict__ R0,
                                            float* __restrict__ R,
                                            float* __restrict__ Z,
                                            const float* __restrict__ csPrev,
                                            float* __restrict__ csNext,
                                            int z_zero, int last) {
  __shared__ float s_scale[NN];       // 4 KB
  __shared__ float s_part[WPB * NN];  // 16 KB
  const int lane = threadIdx.x & 63;
  const int wv = threadIdx.x >> 6;

  // Phase 0: scale[col] = max(1 - SCLC/(sqrt(sum_k cs[k][col]) + EPS), 0)
  {
    const int col = threadIdx.x * 4;
    float4 a = make_float4(0.f, 0.f, 0.f, 0.f);
#pragma unroll
    for (int k = 0; k < KSLOT; ++k) {
      const float4 v = *(const float4*)(csPrev + (size_t)k * NN + col);
      a.x += v.x; a.y += v.y; a.z += v.z; a.w += v.w;
    }
    s_scale[col + 0] = fmaxf(1.0f - SCLC / (sqrtf(a.x) + EPSL), 0.0f);
    s_scale[col + 1] = fmaxf(1.0f - SCLC / (sqrtf(a.y) + EPSL), 0.0f);
    s_scale[col + 2] = fmaxf(1.0f - SCLC / (sqrtf(a.z) + EPSL), 0.0f);
    s_scale[col + 3] = fmaxf(1.0f - SCLC / (sqrtf(a.w) + EPSL), 0.0f);
  }
  __syncthreads();

#pragma unroll
  for (int rr = 0; rr < RPW; ++rr) {
    const size_t row = (size_t)blockIdx.x * RPB + wv * RPW + rr;
    const size_t base = row * NN + (size_t)lane * 4;
    float t[4][4], zn[4][4];
    float mloc = -3.4e38f;
#pragma unroll
    for (int c = 0; c < 4; ++c) {
      const int coff = c * 256 + lane * 4;
      const float4 sc4 = *(const float4*)(&s_scale[coff]);  // LDS
      const float4 rv4 = *(const float4*)(R + base + c * 256);
      const float4 r04 = *(const float4*)(R0 + base + c * 256);
      float zv[4] = {0.f, 0.f, 0.f, 0.f};
      if (!z_zero) {
        const float4 z4 = *(const float4*)(Z + base + c * 256);
        zv[0] = z4.x; zv[1] = z4.y; zv[2] = z4.z; zv[3] = z4.w;
      }
      const float sc[4] = {sc4.x, sc4.y, sc4.z, sc4.w};
      const float rv[4] = {rv4.x, rv4.y, rv4.z, rv4.w};
      const float r0[4] = {r04.x, r04.y, r04.z, r04.w};
#pragma unroll
      for (int j = 0; j < 4; ++j) {
        const float x = rv[j] + zv[j];          // R + Z/RHO, RHO=1
        const float s = softthr(x);
        const float X = sc[j] * s;              // X_t (never stored)
        zn[c][j] = zv[j] + (rv[j] - X);         // Z_t
        const float l0 = logf(r0[j] == 0.f ? MINV : r0[j]);
        const float lX = logf(X == 0.f ? MINV : X);
        t[c][j] = 0.5f * (l0 + lX - zn[c][j]);  // (log R0' + log X' - Z)/2
        mloc = fmaxf(mloc, t[c][j]);
      }
    }
    const float mx = wred_max(mloc);
    float sloc = 0.f;
#pragma unroll
    for (int c = 0; c < 4; ++c)
#pragma unroll
      for (int j = 0; j < 4; ++j) {
        t[c][j] = expf(t[c][j] - mx);
        sloc += t[c][j];
      }
    const float inv = 1.0f / wred_sum(sloc);
#pragma unroll
    for (int c = 0; c < 4; ++c) {
      float rn[4];
#pragma unroll
      for (int j = 0; j < 4; ++j) rn[j] = t[c][j] * inv;  // R_{t+1}
      *(float4*)(R + base + c * 256) = make_float4(rn[0], rn[1], rn[2], rn[3]);
      if (!last) {
        *(float4*)(Z + base + c * 256) =
            make_float4(zn[c][0], zn[c][1], zn[c][2], zn[c][3]);
        float a[4];
#pragma unroll
        for (int j = 0; j < 4; ++j) {
          const float s = softthr(rn[j] + zn[c][j]);  // next iter's s_td
          a[j] = s * s;
        }
        float* p = &s_part[wv * NN + c * 256 + lane * 4];
        if (rr == 0) {
          *(float4*)p = make_float4(a[0], a[1], a[2], a[3]);
        } else {
          float4 o = *(float4*)p;
          *(float4*)p =
              make_float4(o.x + a[0], o.y + a[1], o.z + a[2], o.w + a[3]);
        }
      }
    }
  }
  if (!last) {
    __syncthreads();
    const int col = threadIdx.x * 4;
    float4 s0 = *(float4*)(&s_part[0 * NN + col]);
    float4 s1 = *(float4*)(&s_part[1 * NN + col]);
    float4 s2 = *(float4*)(&s_part[2 * NN + col]);
    float4 s3 = *(float4*)(&s_part[3 * NN + col]);
    float* dst = csNext + (size_t)(blockIdx.x & (KSLOT - 1)) * NN + col;
    atomicAdd(dst + 0, (s0.x + s1.x) + (s2.x + s3.x));
    atomicAdd(dst + 1, (s0.y + s1.y) + (s2.y + s3.y));
    atomicAdd(dst + 2, (s0.z + s1.z) + (s2.z + s3.z));
    atomicAdd(dst + 3, (s0.w + s1.w) + (s2.w + s3.w));
  }
}

extern "C" void kernel_launch(void* const* d_in, const int* in_sizes, int n_in,
                              void* d_out, int out_size, void* d_ws, size_t ws_size,
                              hipStream_t stream) {
  (void)in_sizes; (void)n_in; (void)out_size; (void)ws_size;
  const float* R0 = (const float*)d_in[0];
  float* R = (float*)d_out;                 // final R_20 lands in d_out
  float* Z = (float*)d_ws;                  // 64 MB
  // 20 colsum slices, each KSLOT sub-slots of NN floats (1.25 MB total).
  // Slice t accumulated in iter t, summed+read in iter t+1. Zeroed once.
  float* cs = (float*)((char*)d_ws + (size_t)NROWS * NN * sizeof(float));

  hipMemsetAsync(cs, 0, 20 * KSLOT * NN * sizeof(float), stream);
  k_start<<<NGRID, TPB, 0, stream>>>(R0, R, cs);
  for (int it = 1; it < 20; ++it) {
    k_ab<<<NGRID, TPB, 0, stream>>>(R0, R, Z,
                                    cs + (size_t)(it - 1) * KSLOT * NN,
                                    cs + (size_t)it * KSLOT * NN,
                                    (it == 1) ? 1 : 0, (it == 19) ? 1 : 0);
  }
}

// Round 6
// 1108.272 us; speedup vs baseline: 7.0448x; 1.2557x over previous
//
#include <hip/hip_runtime.h>
#include <math.h>

// Problem: B=16, M=1024, N=1024 fp32; 20 ADMM iterations.
// RHO=1, LAMBD=0.1, ALPHA=0.5 -> threshold = 0.05, scale-const = 0.05.
//
// State collapse: V_t = R_t + Z_{t-1} is the ONLY per-element state.
//   X_t = sc_t * softthr(V_t);  Z_t = V_t - X_t  (recovered, never stored)
//   R_{t+1} = normalize(sqrt(R0') * sqrt(X_t') * exp(-Z_t/2))   [= the
//   reference softmax((log R0' + log X' - Z)/(1+RHO)) with RHO=1, no logs,
//   no max-subtraction needed: u in [~1e-20, ~1]]
//   V_{t+1} = R_{t+1} + Z_t;  colsum s_td = softthr(V_{t+1})
// NOTE: two separate sqrts — sqrt(R0*X) would denormal-flush to 0 at X=MINV.
// V lives in d_out; last iteration writes R_20 there instead of V_20.
#define NN 1024
#define NROWS 16384
#define TPB 256           // 4 waves/block
#define WPB 4
#define RPW 2             // rows per wave
#define RPB (WPB * RPW)   // 8 rows per block
#define NGRID (NROWS / RPB)  // 2048 blocks (R4-proven)
#define KSLOT 16          // atomic spread: chain = 2048/16 = 128/address
#define NIT 20

#define MINV 1e-40f
#define THR  0.05f   // ALPHA*LAMBD/RHO
#define SCLC 0.05f   // (1-ALPHA)*LAMBD/RHO
#define EPSL 1e-10f

__device__ __forceinline__ float wred_sum(float v) {
#pragma unroll
  for (int o = 32; o > 0; o >>= 1) v += __shfl_xor(v, o, 64);
  return v;
}
__device__ __forceinline__ float softthr(float x) {
  return copysignf(fmaxf(fabsf(x) - THR, 0.0f), x);
}

// Layout: row = blockIdx.x*8 + wave*2 + rr; lane L covers cols {c*256+L*4+j}.
// All global accesses are coalesced float4.

// Step 1: Z_0=0, X=R0 -> tmp = log R0', so R_1 = R0'/rowsum(R0') (softmax of
// log is just normalization). V_1 = R_1. Also store SQ = sqrt(R0') and
// accumulate cs[0] = colsum softthr(V_1)^2.
__global__ __launch_bounds__(TPB) void k_start(const float* __restrict__ R0,
                                               float* __restrict__ V,
                                               float* __restrict__ SQ,
                                               float* __restrict__ cs0) {
  __shared__ float s_part[WPB * NN];  // 16 KB
  const int lane = threadIdx.x & 63;
  const int wv = threadIdx.x >> 6;
#pragma unroll
  for (int rr = 0; rr < RPW; ++rr) {
    const size_t row = (size_t)blockIdx.x * RPB + wv * RPW + rr;
    const size_t base = row * NN + (size_t)lane * 4;
    float r0v[16];
    float sloc = 0.f;
#pragma unroll
    for (int c = 0; c < 4; ++c) {
      const float4 r4 = *(const float4*)(R0 + base + c * 256);
      float* p = &r0v[c * 4];
      p[0] = (r4.x == 0.f) ? MINV : r4.x;
      p[1] = (r4.y == 0.f) ? MINV : r4.y;
      p[2] = (r4.z == 0.f) ? MINV : r4.z;
      p[3] = (r4.w == 0.f) ? MINV : r4.w;
      sloc += (p[0] + p[1]) + (p[2] + p[3]);
      *(float4*)(SQ + base + c * 256) =
          make_float4(sqrtf(p[0]), sqrtf(p[1]), sqrtf(p[2]), sqrtf(p[3]));
    }
    const float inv = 1.0f / wred_sum(sloc);
#pragma unroll
    for (int c = 0; c < 4; ++c) {
      float rn[4], a[4];
#pragma unroll
      for (int j = 0; j < 4; ++j) {
        rn[j] = r0v[c * 4 + j] * inv;   // V_1 = R_1 (Z_0 = 0)
        const float s = softthr(rn[j]);
        a[j] = s * s;
      }
      *(float4*)(V + base + c * 256) = make_float4(rn[0], rn[1], rn[2], rn[3]);
      float* sp = &s_part[wv * NN + c * 256 + lane * 4];
      if (rr == 0) {
        *(float4*)sp = make_float4(a[0], a[1], a[2], a[3]);
      } else {
        float4 o = *(float4*)sp;
        *(float4*)sp = make_float4(o.x + a[0], o.y + a[1], o.z + a[2], o.w + a[3]);
      }
    }
  }
  __syncthreads();
  const int col = threadIdx.x * 4;
  const float4 s0 = *(float4*)(&s_part[0 * NN + col]);
  const float4 s1 = *(float4*)(&s_part[1 * NN + col]);
  const float4 s2 = *(float4*)(&s_part[2 * NN + col]);
  const float4 s3 = *(float4*)(&s_part[3 * NN + col]);
  float* dst = cs0 + (size_t)(blockIdx.x & (KSLOT - 1)) * NN + col;
  atomicAdd(dst + 0, (s0.x + s1.x) + (s2.x + s3.x));
  atomicAdd(dst + 1, (s0.y + s1.y) + (s2.y + s3.y));
  atomicAdd(dst + 2, (s0.z + s1.z) + (s2.z + s3.z));
  atomicAdd(dst + 3, (s0.w + s1.w) + (s2.w + s3.w));
}

// Iteration t (t=1..19): scale from csPrev; V_t -> X_t, Z_t, R_{t+1};
// write V_{t+1} (or R_20 if last); accumulate csNext = colsum softthr(V')^2.
__global__ __launch_bounds__(TPB) void k_ab(float* __restrict__ V,
                                            const float* __restrict__ SQ,
                                            const float* __restrict__ csPrev,
                                            float* __restrict__ csNext,
                                            int last) {
  __shared__ float s_scale[NN];       // 4 KB
  __shared__ float s_part[WPB * NN];  // 16 KB
  const int lane = threadIdx.x & 63;
  const int wv = threadIdx.x >> 6;

  // Phase 0: scale[col] = max(1 - SCLC/(sqrt(sum_k cs[k][col]) + EPS), 0)
  {
    const int col = threadIdx.x * 4;
    float4 a = make_float4(0.f, 0.f, 0.f, 0.f);
#pragma unroll
    for (int k = 0; k < KSLOT; ++k) {
      const float4 v = *(const float4*)(csPrev + (size_t)k * NN + col);
      a.x += v.x; a.y += v.y; a.z += v.z; a.w += v.w;
    }
    s_scale[col + 0] = fmaxf(1.0f - SCLC / (sqrtf(a.x) + EPSL), 0.0f);
    s_scale[col + 1] = fmaxf(1.0f - SCLC / (sqrtf(a.y) + EPSL), 0.0f);
    s_scale[col + 2] = fmaxf(1.0f - SCLC / (sqrtf(a.z) + EPSL), 0.0f);
    s_scale[col + 3] = fmaxf(1.0f - SCLC / (sqrtf(a.w) + EPSL), 0.0f);
  }
  __syncthreads();

#pragma unroll
  for (int rr = 0; rr < RPW; ++rr) {
    const size_t row = (size_t)blockIdx.x * RPB + wv * RPW + rr;
    const size_t base = row * NN + (size_t)lane * 4;
    float u[16], z[16];
    float sloc = 0.f;
#pragma unroll
    for (int c = 0; c < 4; ++c) {
      const float4 vv4 = *(const float4*)(V + base + c * 256);
      const float4 sq4 = *(const float4*)(SQ + base + c * 256);
      const float4 sc4 = *(const float4*)(&s_scale[c * 256 + lane * 4]);
      const float vv[4] = {vv4.x, vv4.y, vv4.z, vv4.w};
      const float sq[4] = {sq4.x, sq4.y, sq4.z, sq4.w};
      const float sc[4] = {sc4.x, sc4.y, sc4.z, sc4.w};
#pragma unroll
      for (int j = 0; j < 4; ++j) {
        const float s = softthr(vv[j]);
        const float X = sc[j] * s;              // X_t (never stored)
        const float zz = vv[j] - X;             // Z_t (recovered from V)
        z[c * 4 + j] = zz;
        const float Xm = (X == 0.f) ? MINV : X;
        // u = exp((log R0' + log X' - Z)/2) = sqrt(R0')*sqrt(X')*exp(-Z/2)
        const float uu = sq[j] * sqrtf(Xm) * __expf(-0.5f * zz);
        u[c * 4 + j] = uu;
        sloc += uu;
      }
    }
    const float inv = 1.0f / wred_sum(sloc);
#pragma unroll
    for (int c = 0; c < 4; ++c) {
      float outv[4];
#pragma unroll
      for (int j = 0; j < 4; ++j) {
        const float rn = u[c * 4 + j] * inv;    // R_{t+1}
        outv[j] = last ? rn : (rn + z[c * 4 + j]);  // R_20 or V_{t+1}
      }
      *(float4*)(V + base + c * 256) =
          make_float4(outv[0], outv[1], outv[2], outv[3]);
      if (!last) {
        float a[4];
#pragma unroll
        for (int j = 0; j < 4; ++j) {
          const float s = softthr(outv[j]);     // next iter's s_td
          a[j] = s * s;
        }
        float* sp = &s_part[wv * NN + c * 256 + lane * 4];
        if (rr == 0) {
          *(float4*)sp = make_float4(a[0], a[1], a[2], a[3]);
        } else {
          float4 o = *(float4*)sp;
          *(float4*)sp =
              make_float4(o.x + a[0], o.y + a[1], o.z + a[2], o.w + a[3]);
        }
      }
    }
  }
  if (!last) {
    __syncthreads();
    const int col = threadIdx.x * 4;
    const float4 s0 = *(float4*)(&s_part[0 * NN + col]);
    const float4 s1 = *(float4*)(&s_part[1 * NN + col]);
    const float4 s2 = *(float4*)(&s_part[2 * NN + col]);
    const float4 s3 = *(float4*)(&s_part[3 * NN + col]);
    float* dst = csNext + (size_t)(blockIdx.x & (KSLOT - 1)) * NN + col;
    atomicAdd(dst + 0, (s0.x + s1.x) + (s2.x + s3.x));
    atomicAdd(dst + 1, (s0.y + s1.y) + (s2.y + s3.y));
    atomicAdd(dst + 2, (s0.z + s1.z) + (s2.z + s3.z));
    atomicAdd(dst + 3, (s0.w + s1.w) + (s2.w + s3.w));
  }
}

extern "C" void kernel_launch(void* const* d_in, const int* in_sizes, int n_in,
                              void* d_out, int out_size, void* d_ws, size_t ws_size,
                              hipStream_t stream) {
  (void)in_sizes; (void)n_in; (void)out_size; (void)ws_size;
  const float* R0 = (const float*)d_in[0];
  float* V = (float*)d_out;   // V_t iterates in place; final write = R_20
  float* SQ = (float*)d_ws;   // 64 MB: sqrt(R0'), iteration-invariant
  // 20 colsum slices x KSLOT sub-slots x NN floats = 1.25 MB, zeroed once.
  float* cs = (float*)((char*)d_ws + (size_t)NROWS * NN * sizeof(float));

  hipMemsetAsync(cs, 0, (size_t)NIT * KSLOT * NN * sizeof(float), stream);
  k_start<<<NGRID, TPB, 0, stream>>>(R0, V, SQ, cs);
  for (int it = 1; it < NIT; ++it) {
    k_ab<<<NGRID, TPB, 0, stream>>>(V, SQ,
                                    cs + (size_t)(it - 1) * KSLOT * NN,
                                    cs + (size_t)it * KSLOT * NN,
                                    (it == NIT - 1) ? 1 : 0);
  }
}